// Round 14
// baseline (20.584 us; speedup 1.0000x reference)
//
#include <hip/hip_runtime.h>
#include <math.h>

#define SEQ   32768
#define DENC  200
#define NH    8192

#define K1B       64
#define K1T       1024
#define K1ROWS_PB (NH / K1B)             // 128 rows per block
#define K1ROWS_PG (K1ROWS_PB / 4)        // 32 rows per 256-thread group

#define K2B    512
#define K2T    512                       // 8 waves
#define K2ROWS (SEQ / K2B)               // 64 rows per block
#define RPW    8                         // rows per wave

#define K3B    (SEQ / 256)               // 128

typedef float f4 __attribute__((ext_vector_type(4)));

// ws layout: double ws_sum[K2B]; float ws_v[K1B*DENC]; float ws_e[SEQ].
// Everything fully rewritten every launch; no zeroing, no atomics,
// no cross-block communication inside any kernel (G16).

__device__ __forceinline__ double wave_sum_d(double x) {
    #pragma unroll
    for (int off = 32; off; off >>= 1) x += __shfl_xor(x, off, 64);
    return x;
}
__device__ __forceinline__ float wave_sum(float x) {
    #pragma unroll
    for (int off = 32; off; off >>= 1) x += __shfl_xor(x, off, 64);
    return x;
}
// exp(e) as double via 2^n * 2^frac (no max pass; |e| ~< 300 << 709)
__device__ __forceinline__ double exp_d(float e) {
    const float f = e * 1.4426950408889634f;
    const float n = rintf(f);
    const float m = exp2f(f - n);                 // v_exp_f32
    const long long eb = ((long long)(1023 + (int)n)) << 52;
    return (double)m * __longlong_as_double(eb);  // exact 2^n scale
}

// ---- K1: 64 plain-stored v-partial banks (no atomics, no memset).
__global__ __launch_bounds__(K1T) void k1_proj(const float* __restrict__ W,
                                               const float* __restrict__ hidden,
                                               float* __restrict__ ws_v) {
    __shared__ float part[4][DENC];
    const int t = threadIdx.x, b = blockIdx.x;
    const int g = t >> 8, lt = t & 255;
    const int h0 = b * K1ROWS_PB + g * K1ROWS_PG;

    if (lt < DENC) {
        float acc = 0.f;
        #pragma unroll 8
        for (int i = 0; i < K1ROWS_PG; ++i)
            acc = fmaf(__builtin_nontemporal_load(&W[(size_t)(h0 + i) * DENC + lt]),
                       hidden[h0 + i], acc);
        part[g][lt] = acc;
    }
    __syncthreads();
    if (t < DENC)
        ws_v[b * DENC + t] = (part[0][t] + part[1][t]) + (part[2][t] + part[3][t]);
}

// ---- K2: energies from register-preloaded enc rows; v reduced from 64 banks;
// float energies stored; block exp-sums in double.
__global__ __launch_bounds__(K2T) void k2_energy(const float* __restrict__ enc,
                                                 const float* __restrict__ ws_v,
                                                 float* __restrict__ ws_e,
                                                 double* __restrict__ ws_sum) {
    __shared__ float  v_lds[DENC];
    __shared__ double s_lds[K2T / 64];
    const int t = threadIdx.x, b = blockIdx.x;
    const int lane = t & 63, wid = t >> 6;
    const bool act = (lane < 50);

    // enc loads first: they are the long pole (read-once -> nontemporal)
    const int s0 = b * K2ROWS + wid * RPW;
    const float* ebase = enc + (size_t)s0 * DENC + lane * 4;
    #define LD(i) __builtin_nontemporal_load((const f4*)(act ? ebase + (i)*DENC : enc))
    f4 q0 = LD(0); f4 q1 = LD(1); f4 q2 = LD(2); f4 q3 = LD(3);
    f4 q4 = LD(4); f4 q5 = LD(5); f4 q6 = LD(6); f4 q7 = LD(7);
    #undef LD

    // v from 64 float banks: 51.2KB per block, L2-resident, coalesced
    if (t < DENC) {
        float a0 = 0.f, a1 = 0.f, a2 = 0.f, a3 = 0.f;
        const float* p = ws_v + t;
        #pragma unroll 4
        for (int k = 0; k < K1B; k += 4) {
            a0 += p[(size_t)(k + 0) * DENC];
            a1 += p[(size_t)(k + 1) * DENC];
            a2 += p[(size_t)(k + 2) * DENC];
            a3 += p[(size_t)(k + 3) * DENC];
        }
        v_lds[t] = (a0 + a1) + (a2 + a3);
    }
    __syncthreads();

    f4 v4 = {0.f, 0.f, 0.f, 0.f};
    if (act) v4 = *(const f4*)(v_lds + lane * 4);

    float e0,e1,e2,e3,e4,e5,e6,e7;
    #define DOT(qi, ei) { \
        float d = act ? (qi.x*v4.x + qi.y*v4.y + qi.z*v4.z + qi.w*v4.w) : 0.f; \
        ei = wave_sum(d); }
    DOT(q0,e0) DOT(q1,e1) DOT(q2,e2) DOT(q3,e3)
    DOT(q4,e4) DOT(q5,e5) DOT(q6,e6) DOT(q7,e7)
    #undef DOT

    // lanes 0..7 own rows s0..s0+7
    float e = e0;
    e = (lane == 1) ? e1 : e;  e = (lane == 2) ? e2 : e;
    e = (lane == 3) ? e3 : e;  e = (lane == 4) ? e4 : e;
    e = (lane == 5) ? e5 : e;  e = (lane == 6) ? e6 : e;
    e = (lane == 7) ? e7 : e;
    double ps = 0.0;
    if (lane < 8) {
        ws_e[s0 + lane] = e;                       // float energies: 32B/wave
        ps = exp_d(e);
    }
    double p = ps;                                 // 8-lane group sum
    p += __shfl_xor(p, 1, 64);
    p += __shfl_xor(p, 2, 64);
    p += __shfl_xor(p, 4, 64);
    if (lane == 0) s_lds[wid] = p;
    __syncthreads();
    if (t == 0) {
        double S = 0.0;
        #pragma unroll
        for (int w = 0; w < K2T / 64; ++w) S += s_lds[w];
        ws_sum[b] = S;
    }
}

// ---- K3: redundant global-sum reduce (4KB, L2), recompute exp, normalize.
__global__ __launch_bounds__(256) void k3_norm(const float* __restrict__ ws_e,
                                               const double* __restrict__ ws_sum,
                                               float* __restrict__ out) {
    __shared__ double s_lds[4];
    __shared__ double inv_lds;
    const int t = threadIdx.x, b = blockIdx.x;
    const int lane = t & 63, wid = t >> 6;

    double a = ws_sum[t] + ws_sum[t + 256];        // K2B=512 -> 2 per thread
    a = wave_sum_d(a);
    if (lane == 0) s_lds[wid] = a;
    __syncthreads();
    if (t == 0) inv_lds = 1.0 / ((s_lds[0] + s_lds[1]) + (s_lds[2] + s_lds[3]));
    __syncthreads();

    const int i = b * 256 + t;
    out[i] = (float)(exp_d(ws_e[i]) * inv_lds);
}

extern "C" void kernel_launch(void* const* d_in, const int* in_sizes, int n_in,
                              void* d_out, int out_size, void* d_ws, size_t ws_size,
                              hipStream_t stream) {
    const float* hidden = (const float*)d_in[0];   // [H]
    const float* enc    = (const float*)d_in[1];   // [SEQ, DENC]
    const float* W      = (const float*)d_in[2];   // [H, 200]
    float* out = (float*)d_out;

    double* ws_sum = (double*)d_ws;                // [K2B]
    float*  ws_v   = (float*)(ws_sum + K2B);       // [K1B*DENC]
    float*  ws_e   = ws_v + (size_t)K1B * DENC;    // [SEQ]

    k1_proj  <<<K1B, K1T, 0, stream>>>(W, hidden, ws_v);
    k2_energy<<<K2B, K2T, 0, stream>>>(enc, ws_v, ws_e, ws_sum);
    k3_norm  <<<K3B, 256, 0, stream>>>(ws_e, ws_sum, out);
}

// Round 15
// 19.319 us; speedup vs baseline: 1.0654x; 1.0654x over previous
//
#include <hip/hip_runtime.h>
#include <math.h>

#define SEQ   32768
#define DENC  200
#define NH    8192

#define K1B       64
#define K1T       1024
#define K1ROWS_PB (NH / K1B)             // 128 rows per block
#define K1ROWS_PG (K1ROWS_PB / 4)        // 32 rows per 256-thread group

#define K2B    512
#define K2T    512                       // 8 waves
#define K2ROWS (SEQ / K2B)               // 64 rows per block
#define RPW    8                         // rows per wave

#define K3B    (SEQ / 256)               // 128

// ws layout: double ws_sum[K2B]; float ws_v[K1B*DENC]; float ws_e[SEQ].
// Everything fully rewritten every launch; no zeroing, no atomics,
// no cross-block communication inside any kernel (G16), no NT loads
// (inputs are L3-resident across graph replays).

__device__ __forceinline__ double wave_sum_d(double x) {
    #pragma unroll
    for (int off = 32; off; off >>= 1) x += __shfl_xor(x, off, 64);
    return x;
}
__device__ __forceinline__ float wave_sum(float x) {
    #pragma unroll
    for (int off = 32; off; off >>= 1) x += __shfl_xor(x, off, 64);
    return x;
}
// exp(e) as double via 2^n * 2^frac (no max pass; |e| ~< 300 << 709)
__device__ __forceinline__ double exp_d(float e) {
    const float f = e * 1.4426950408889634f;
    const float n = rintf(f);
    const float m = exp2f(f - n);                 // v_exp_f32
    const long long eb = ((long long)(1023 + (int)n)) << 52;
    return (double)m * __longlong_as_double(eb);  // exact 2^n scale
}

// ---- K1: 64 plain-stored v-partial banks (no atomics, no memset).
__global__ __launch_bounds__(K1T) void k1_proj(const float* __restrict__ W,
                                               const float* __restrict__ hidden,
                                               float* __restrict__ ws_v) {
    __shared__ float part[4][DENC];
    const int t = threadIdx.x, b = blockIdx.x;
    const int g = t >> 8, lt = t & 255;
    const int h0 = b * K1ROWS_PB + g * K1ROWS_PG;

    if (lt < DENC) {
        float acc = 0.f;
        #pragma unroll 8
        for (int i = 0; i < K1ROWS_PG; ++i)
            acc = fmaf(W[(size_t)(h0 + i) * DENC + lt], hidden[h0 + i], acc);
        part[g][lt] = acc;
    }
    __syncthreads();
    if (t < DENC)
        ws_v[b * DENC + t] = (part[0][t] + part[1][t]) + (part[2][t] + part[3][t]);
}

// ---- K2: energies from register-preloaded enc rows; v reduced from 64 banks;
// float energies stored; block exp-sums in double.
__global__ __launch_bounds__(K2T) void k2_energy(const float* __restrict__ enc,
                                                 const float* __restrict__ ws_v,
                                                 float* __restrict__ ws_e,
                                                 double* __restrict__ ws_sum) {
    __shared__ float  v_lds[DENC];
    __shared__ double s_lds[K2T / 64];
    const int t = threadIdx.x, b = blockIdx.x;
    const int lane = t & 63, wid = t >> 6;
    const bool act = (lane < 50);

    // enc loads first: they are the long pole
    const int s0 = b * K2ROWS + wid * RPW;
    const float* ebase = enc + (size_t)s0 * DENC + lane * 4;
    float4 q0 = *(const float4*)(act ? ebase + 0*DENC : enc);
    float4 q1 = *(const float4*)(act ? ebase + 1*DENC : enc);
    float4 q2 = *(const float4*)(act ? ebase + 2*DENC : enc);
    float4 q3 = *(const float4*)(act ? ebase + 3*DENC : enc);
    float4 q4 = *(const float4*)(act ? ebase + 4*DENC : enc);
    float4 q5 = *(const float4*)(act ? ebase + 5*DENC : enc);
    float4 q6 = *(const float4*)(act ? ebase + 6*DENC : enc);
    float4 q7 = *(const float4*)(act ? ebase + 7*DENC : enc);

    // v from 64 float banks: 51.2KB per block, L2-resident, coalesced
    if (t < DENC) {
        float a0 = 0.f, a1 = 0.f, a2 = 0.f, a3 = 0.f;
        const float* p = ws_v + t;
        #pragma unroll 4
        for (int k = 0; k < K1B; k += 4) {
            a0 += p[(size_t)(k + 0) * DENC];
            a1 += p[(size_t)(k + 1) * DENC];
            a2 += p[(size_t)(k + 2) * DENC];
            a3 += p[(size_t)(k + 3) * DENC];
        }
        v_lds[t] = (a0 + a1) + (a2 + a3);
    }
    __syncthreads();

    float4 v4 = make_float4(0.f, 0.f, 0.f, 0.f);
    if (act) v4 = *(const float4*)(v_lds + lane * 4);

    float e0,e1,e2,e3,e4,e5,e6,e7;
    #define DOT(qi, ei) { \
        float d = act ? (qi.x*v4.x + qi.y*v4.y + qi.z*v4.z + qi.w*v4.w) : 0.f; \
        ei = wave_sum(d); }
    DOT(q0,e0) DOT(q1,e1) DOT(q2,e2) DOT(q3,e3)
    DOT(q4,e4) DOT(q5,e5) DOT(q6,e6) DOT(q7,e7)
    #undef DOT

    // lanes 0..7 own rows s0..s0+7
    float e = e0;
    e = (lane == 1) ? e1 : e;  e = (lane == 2) ? e2 : e;
    e = (lane == 3) ? e3 : e;  e = (lane == 4) ? e4 : e;
    e = (lane == 5) ? e5 : e;  e = (lane == 6) ? e6 : e;
    e = (lane == 7) ? e7 : e;
    double ps = 0.0;
    if (lane < 8) {
        ws_e[s0 + lane] = e;                       // float energies: 32B/wave
        ps = exp_d(e);
    }
    double p = ps;                                 // 8-lane group sum
    p += __shfl_xor(p, 1, 64);
    p += __shfl_xor(p, 2, 64);
    p += __shfl_xor(p, 4, 64);
    if (lane == 0) s_lds[wid] = p;
    __syncthreads();
    if (t == 0) {
        double S = 0.0;
        #pragma unroll
        for (int w = 0; w < K2T / 64; ++w) S += s_lds[w];
        ws_sum[b] = S;
    }
}

// ---- K3: redundant global-sum reduce (4KB, L2), recompute exp, normalize.
__global__ __launch_bounds__(256) void k3_norm(const float* __restrict__ ws_e,
                                               const double* __restrict__ ws_sum,
                                               float* __restrict__ out) {
    __shared__ double s_lds[4];
    __shared__ double inv_lds;
    const int t = threadIdx.x, b = blockIdx.x;
    const int lane = t & 63, wid = t >> 6;

    double a = ws_sum[t] + ws_sum[t + 256];        // K2B=512 -> 2 per thread
    a = wave_sum_d(a);
    if (lane == 0) s_lds[wid] = a;
    __syncthreads();
    if (t == 0) inv_lds = 1.0 / ((s_lds[0] + s_lds[1]) + (s_lds[2] + s_lds[3]));
    __syncthreads();

    const int i = b * 256 + t;
    out[i] = (float)(exp_d(ws_e[i]) * inv_lds);
}

extern "C" void kernel_launch(void* const* d_in, const int* in_sizes, int n_in,
                              void* d_out, int out_size, void* d_ws, size_t ws_size,
                              hipStream_t stream) {
    const float* hidden = (const float*)d_in[0];   // [H]
    const float* enc    = (const float*)d_in[1];   // [SEQ, DENC]
    const float* W      = (const float*)d_in[2];   // [H, 200]
    float* out = (float*)d_out;

    double* ws_sum = (double*)d_ws;                // [K2B]
    float*  ws_v   = (float*)(ws_sum + K2B);       // [K1B*DENC]
    float*  ws_e   = ws_v + (size_t)K1B * DENC;    // [SEQ]

    k1_proj  <<<K1B, K1T, 0, stream>>>(W, hidden, ws_v);
    k2_energy<<<K2B, K2T, 0, stream>>>(enc, ws_v, ws_e, ws_sum);
    k3_norm  <<<K3B, 256, 0, stream>>>(ws_e, ws_sum, out);
}